// Round 5
// baseline (300.501 us; speedup 1.0000x reference)
//
#include <hip/hip_runtime.h>
#include <math.h>

#define BB 4
#define CC 256
#define DD 32
#define NN 4096

typedef __attribute__((ext_vector_type(8))) short short8;
typedef __attribute__((ext_vector_type(4))) float floatx4;
typedef __attribute__((ext_vector_type(4))) int intx4;

#define SCALEF (0.17677669529663687f * 1.4426950408889634f)  // 1/sqrt(32)*log2(e)

// float -> bf16 round-to-nearest-even
__device__ __forceinline__ ushort f2bf(float f) {
    unsigned int u = __builtin_bit_cast(unsigned int, f);
    u += 0x7FFFu + ((u >> 16) & 1u);
    return (ushort)(u >> 16);
}
// pack two floats' bf16 truncations into one dword with a single v_perm_b32
// (low short = a, high short = b; convention validated R2->R4)
__device__ __forceinline__ int pk_trunc(float a, float b) {
    return (int)__builtin_amdgcn_perm(__builtin_bit_cast(unsigned, b),
                                      __builtin_bit_cast(unsigned, a),
                                      0x07060302u);
}
__device__ __forceinline__ float fast_exp2(float x) {
#if __has_builtin(__builtin_amdgcn_exp2f)
    return __builtin_amdgcn_exp2f(x);
#else
    return exp2f(x);
#endif
}

// ---------------------------------------------------------------------------
// Kernel 1: MFMA QKV projection.  One wave per block computes a 64o x 64n
// tile of [Wq;Wk;Wv](320x256) @ x(256x4096).  A-frags: 8 scalar fp32 W loads
// + v_perm pack (W is L1/L2-hot).  B-frags: 8 scalar fp32 x loads (stride N)
// + pack — no LDS, no transpose.  q-scale*log2e folded into Wq frags & bq.
// Outputs bf16: qb,kb (B,N,32), vb (B,C,N).
// ---------------------------------------------------------------------------
__global__ __launch_bounds__(64) void qkv_mfma(
    const float* __restrict__ x,
    const float* __restrict__ Wq, const float* __restrict__ bq,
    const float* __restrict__ Wk, const float* __restrict__ bk,
    const float* __restrict__ Wv, const float* __restrict__ bv,
    ushort* __restrict__ qb, ushort* __restrict__ kb, ushort* __restrict__ vb)
{
    const int lane = threadIdx.x;
    const int l15 = lane & 15, qd = lane >> 4;
    const int b = blockIdx.z, m0 = blockIdx.y * 64, n0 = blockIdx.x * 64;
    const float* xb = x + (size_t)b * CC * NN;
    const bool isqk = (m0 == 0);

    const float* wr[4];
    if (isqk) {
        wr[0] = Wq + (size_t)l15 * CC;
        wr[1] = Wq + (size_t)(16 + l15) * CC;
        wr[2] = Wk + (size_t)l15 * CC;
        wr[3] = Wk + (size_t)(16 + l15) * CC;
    } else {
        #pragma unroll
        for (int f = 0; f < 4; ++f) wr[f] = Wv + (size_t)(m0 - 64 + f * 16 + l15) * CC;
    }

    floatx4 z = {0.f, 0.f, 0.f, 0.f};
    floatx4 acc[4][4];
    #pragma unroll
    for (int i = 0; i < 4; ++i)
        #pragma unroll
        for (int j = 0; j < 4; ++j) acc[i][j] = z;

    for (int k0 = 0; k0 < CC; k0 += 32) {
        short8 af[4], bf[4];
        #pragma unroll
        for (int f = 0; f < 4; ++f) {
            const float* p = wr[f] + k0 + qd * 8;
            float w[8];
            #pragma unroll
            for (int j = 0; j < 8; ++j) w[j] = p[j];
            if (isqk && f < 2) {
                #pragma unroll
                for (int j = 0; j < 8; ++j) w[j] *= SCALEF;
            }
            intx4 d;
            d[0] = pk_trunc(w[0], w[1]); d[1] = pk_trunc(w[2], w[3]);
            d[2] = pk_trunc(w[4], w[5]); d[3] = pk_trunc(w[6], w[7]);
            af[f] = __builtin_bit_cast(short8, d);
        }
        #pragma unroll
        for (int f = 0; f < 4; ++f) {
            const float* p = xb + (size_t)(k0 + qd * 8) * NN + n0 + f * 16 + l15;
            float xv[8];
            #pragma unroll
            for (int j = 0; j < 8; ++j) xv[j] = p[(size_t)j * NN];
            intx4 d;
            d[0] = pk_trunc(xv[0], xv[1]); d[1] = pk_trunc(xv[2], xv[3]);
            d[2] = pk_trunc(xv[4], xv[5]); d[3] = pk_trunc(xv[6], xv[7]);
            bf[f] = __builtin_bit_cast(short8, d);
        }
        #pragma unroll
        for (int fm = 0; fm < 4; ++fm)
            #pragma unroll
            for (int fn = 0; fn < 4; ++fn)
                acc[fm][fn] = __builtin_amdgcn_mfma_f32_16x16x32_bf16(af[fm], bf[fn], acc[fm][fn], 0, 0, 0);
    }

    #pragma unroll
    for (int fm = 0; fm < 4; ++fm) {
        #pragma unroll
        for (int r = 0; r < 4; ++r) {
            int o = m0 + fm * 16 + qd * 4 + r;
            if (isqk) {
                if (fm < 2) {
                    float bo = bq[o] * SCALEF;
                    #pragma unroll
                    for (int fn = 0; fn < 4; ++fn)
                        qb[((size_t)b * NN + n0 + fn * 16 + l15) * DD + o] = f2bf(acc[fm][fn][r] + bo);
                } else {
                    float bo = bk[o - 32];
                    #pragma unroll
                    for (int fn = 0; fn < 4; ++fn)
                        kb[((size_t)b * NN + n0 + fn * 16 + l15) * DD + (o - 32)] = f2bf(acc[fm][fn][r] + bo);
                }
            } else {
                float bo = bv[o - 64];
                #pragma unroll
                for (int fn = 0; fn < 4; ++fn)
                    vb[((size_t)b * CC + (o - 64)) * NN + n0 + fn * 16 + l15] = f2bf(acc[fm][fn][r] + bo);
            }
        }
    }
}

// ---------------------------------------------------------------------------
// Kernel 2: MFMA flash attention, 4-way key-split for occupancy.
// Block = 512 thr = 8 waves = 2 ch-groups x 4 key-quarters; each wave does
// 64 q x 64 ch over 1024 keys (32 tiles).  Partial O and l are additive (no
// max-subtraction), combined via a 3-barrier LDS reduction tree.  Grid
// (8,32,2) = 512 blocks = 2 blocks/CU = 4 waves/SIMD.  XCD-pinned batches.
// ---------------------------------------------------------------------------
__global__ __launch_bounds__(512, 4) void attn_mfma(
    const ushort* __restrict__ qb, const ushort* __restrict__ kb,
    const ushort* __restrict__ vb, ushort* __restrict__ aoT)
{
    __shared__ float red[2][2][4096];   // [cg][slot][((f*4+ct)*4+r)*64 + lane]
    __shared__ float lred[2][2][64];    // [cg][slot][f*16 + q]

    const int t = threadIdx.x;
    const int wave = t >> 6;
    const int lane = t & 63;
    const int l15 = lane & 15;
    const int qd = lane >> 4;
    const int cg = wave & 1;             // ch-group within block
    const int kh = wave >> 1;            // key-quarter 0..3
    const int slot = blockIdx.x;         // ~XCD id (round-robin heuristic)
    const int b = slot >> 1;             // 2 XCDs per batch
    const int qt = (slot & 1) * 32 + blockIdx.y;
    const int q0 = qt * 64;
    const int c0 = (blockIdx.z * 2 + cg) * 64;

    const ushort* krow = kb + ((size_t)b * NN + kh * 1024 + l15) * DD + qd * 8;
    const ushort* vrow = vb + ((size_t)b * CC + c0 + l15) * (size_t)NN + kh * 1024 + qd * 8;

    short8 qf[4];
    #pragma unroll
    for (int f = 0; f < 4; ++f)
        qf[f] = *(const short8*)(qb + ((size_t)b * NN + q0 + f * 16 + l15) * DD + qd * 8);

    const short8 ones = {0x3F80, 0x3F80, 0x3F80, 0x3F80, 0x3F80, 0x3F80, 0x3F80, 0x3F80};

    floatx4 z = {0.f, 0.f, 0.f, 0.f};
    floatx4 acc[4][4];   // [qfrag][chfrag]
    floatx4 accl[4];
    #pragma unroll
    for (int f = 0; f < 4; ++f) {
        accl[f] = z;
        #pragma unroll
        for (int c = 0; c < 4; ++c) acc[f][c] = z;
    }

    const int base  = (qd & 1) * 32 + l15;   // proven transpose lane mapping
    const int base2 = base + 16;
    const bool hi = (lane >= 32);

    // preload first tile of this key-quarter
    short8 kf0 = *(const short8*)(krow);
    short8 kf1 = *(const short8*)(krow + 16 * DD);
    short8 vf[4];
    #pragma unroll
    for (int ct = 0; ct < 4; ++ct)
        vf[ct] = *(const short8*)(vrow + (size_t)ct * 16 * NN);

    for (int kt = 0; kt < 32; ++kt) {
        // prefetch next tile (last iter reads adjacent in-bounds ws; discarded)
        krow += 32 * DD;
        vrow += 32;
        short8 nk0 = *(const short8*)(krow);
        short8 nk1 = *(const short8*)(krow + 16 * DD);
        short8 nvf[4];
        #pragma unroll
        for (int ct = 0; ct < 4; ++ct)
            nvf[ct] = *(const short8*)(vrow + (size_t)ct * 16 * NN);

        floatx4 s0[4], s1[4];
        #pragma unroll
        for (int f = 0; f < 4; ++f) {
            s0[f] = __builtin_amdgcn_mfma_f32_16x16x32_bf16(kf0, qf[f], z, 0, 0, 0);
            s1[f] = __builtin_amdgcn_mfma_f32_16x16x32_bf16(kf1, qf[f], z, 0, 0, 0);
        }

        short8 pt[4];
        #pragma unroll
        for (int f = 0; f < 4; ++f) {
            float e00 = fast_exp2(s0[f][0]), e01 = fast_exp2(s0[f][1]);
            float e02 = fast_exp2(s0[f][2]), e03 = fast_exp2(s0[f][3]);
            float e10 = fast_exp2(s1[f][0]), e11 = fast_exp2(s1[f][1]);
            float e12 = fast_exp2(s1[f][2]), e13 = fast_exp2(s1[f][3]);

            int A0 = pk_trunc(e00, e01);
            int A1 = pk_trunc(e02, e03);
            int B0 = pk_trunc(e10, e11);
            int B1 = pk_trunc(e12, e13);

            int w0a = __shfl(A0, base);  int w0b = __shfl(B0, base);
            int w1a = __shfl(A1, base);  int w1b = __shfl(B1, base);
            int w2a = __shfl(A0, base2); int w2b = __shfl(B0, base2);
            int w3a = __shfl(A1, base2); int w3b = __shfl(B1, base2);

            intx4 ptd;
            ptd[0] = hi ? w0b : w0a;
            ptd[1] = hi ? w1b : w1a;
            ptd[2] = hi ? w2b : w2a;
            ptd[3] = hi ? w3b : w3a;
            pt[f] = __builtin_bit_cast(short8, ptd);
        }

        #pragma unroll
        for (int f = 0; f < 4; ++f)
            accl[f] = __builtin_amdgcn_mfma_f32_16x16x32_bf16(ones, pt[f], accl[f], 0, 0, 0);

        #pragma unroll
        for (int ct = 0; ct < 4; ++ct)
            #pragma unroll
            for (int f = 0; f < 4; ++f)
                acc[f][ct] = __builtin_amdgcn_mfma_f32_16x16x32_bf16(vf[ct], pt[f], acc[f][ct], 0, 0, 0);

        kf0 = nk0; kf1 = nk1;
        #pragma unroll
        for (int ct = 0; ct < 4; ++ct) vf[ct] = nvf[ct];
    }

    float lsum[4];
    #pragma unroll
    for (int f = 0; f < 4; ++f) lsum[f] = accl[f][0];

    // ---- reduction tree over key-quarters: (0+=1, 2+=3), then 0+=2 ----
    // phase A: kh 1,3 publish partials
    if (kh & 1) {
        const int s = kh >> 1;
        #pragma unroll
        for (int f = 0; f < 4; ++f)
            #pragma unroll
            for (int ct = 0; ct < 4; ++ct)
                #pragma unroll
                for (int r = 0; r < 4; ++r)
                    red[cg][s][((f * 4 + ct) * 4 + r) * 64 + lane] = acc[f][ct][r];
        if (qd == 0)
            #pragma unroll
            for (int f = 0; f < 4; ++f) lred[cg][s][f * 16 + l15] = lsum[f];
    }
    __syncthreads();
    if (!(kh & 1)) {
        const int s = kh >> 1;
        #pragma unroll
        for (int f = 0; f < 4; ++f) {
            #pragma unroll
            for (int ct = 0; ct < 4; ++ct)
                #pragma unroll
                for (int r = 0; r < 4; ++r)
                    acc[f][ct][r] += red[cg][s][((f * 4 + ct) * 4 + r) * 64 + lane];
            lsum[f] += lred[cg][s][f * 16 + l15];
        }
    }
    __syncthreads();
    // phase B: kh 2 publishes its combined half
    if (kh == 2) {
        #pragma unroll
        for (int f = 0; f < 4; ++f)
            #pragma unroll
            for (int ct = 0; ct < 4; ++ct)
                #pragma unroll
                for (int r = 0; r < 4; ++r)
                    red[cg][0][((f * 4 + ct) * 4 + r) * 64 + lane] = acc[f][ct][r];
        if (qd == 0)
            #pragma unroll
            for (int f = 0; f < 4; ++f) lred[cg][0][f * 16 + l15] = lsum[f];
    }
    __syncthreads();
    if (kh == 0) {
        #pragma unroll
        for (int f = 0; f < 4; ++f) {
            #pragma unroll
            for (int ct = 0; ct < 4; ++ct)
                #pragma unroll
                for (int r = 0; r < 4; ++r)
                    acc[f][ct][r] += red[cg][0][((f * 4 + ct) * 4 + r) * 64 + lane];
            lsum[f] += lred[cg][0][f * 16 + l15];
        }
        // normalize, write bf16 aoT (B,N,C)
        #pragma unroll
        for (int f = 0; f < 4; ++f) {
            const float inv = 1.0f / lsum[f];
            ushort* dst = aoT + ((size_t)b * NN + q0 + f * 16 + l15) * CC + c0 + qd * 4;
            #pragma unroll
            for (int ct = 0; ct < 4; ++ct) {
                ushort4 h;
                h.x = f2bf(acc[f][ct][0] * inv);
                h.y = f2bf(acc[f][ct][1] * inv);
                h.z = f2bf(acc[f][ct][2] * inv);
                h.w = f2bf(acc[f][ct][3] * inv);
                *(ushort4*)(dst + ct * 16) = h;
            }
        }
    }
}

// ---------------------------------------------------------------------------
// Kernel 3: MFMA output projection + residual.  gemm_bt form, A-frags cast
// from fp32 Wp in-register (8 scalar loads + v_perm pack), B-frags straight
// short8 loads from bf16 aoT (B,N,C).  out = x + gamma*(Wp@ao + bp).
// ---------------------------------------------------------------------------
__global__ __launch_bounds__(256) void proj_mfma(
    const ushort* __restrict__ aoT, const float* __restrict__ Wp,
    const float* __restrict__ bp, const float* __restrict__ x,
    const float* __restrict__ gamma, float* __restrict__ out)
{
    const int t = threadIdx.x;
    const int wave = t >> 6;
    const int lane = t & 63;
    const int l15 = lane & 15;
    const int qd = lane >> 4;
    const int b = blockIdx.z;
    const int m0 = blockIdx.y * 64;
    const int n0 = blockIdx.x * 256 + wave * 64;

    floatx4 z = {0.f, 0.f, 0.f, 0.f};
    floatx4 acc[4][4];   // [fm][fn]
    #pragma unroll
    for (int i = 0; i < 4; ++i)
        #pragma unroll
        for (int j = 0; j < 4; ++j) acc[i][j] = z;

    const ushort* arow = aoT + ((size_t)b * NN + n0 + l15) * CC + qd * 8;
    const float* wrow = Wp + (size_t)(m0 + l15) * CC + qd * 8;

    #pragma unroll
    for (int k0 = 0; k0 < CC; k0 += 32) {
        short8 af[4], bf[4];
        #pragma unroll
        for (int f = 0; f < 4; ++f) {
            const float* p = wrow + (size_t)f * 16 * CC + k0;
            intx4 d;
            d[0] = pk_trunc(p[0], p[1]); d[1] = pk_trunc(p[2], p[3]);
            d[2] = pk_trunc(p[4], p[5]); d[3] = pk_trunc(p[6], p[7]);
            af[f] = __builtin_bit_cast(short8, d);
            bf[f] = *(const short8*)(arow + (size_t)f * 16 * CC + k0);
        }
        #pragma unroll
        for (int fm = 0; fm < 4; ++fm)
            #pragma unroll
            for (int fn = 0; fn < 4; ++fn)
                acc[fm][fn] = __builtin_amdgcn_mfma_f32_16x16x32_bf16(af[fm], bf[fn], acc[fm][fn], 0, 0, 0);
    }

    const float g = gamma[0];
    #pragma unroll
    for (int fm = 0; fm < 4; ++fm) {
        #pragma unroll
        for (int r = 0; r < 4; ++r) {
            int m = m0 + fm * 16 + qd * 4 + r;
            float bpv = bp[m];
            #pragma unroll
            for (int fn = 0; fn < 4; ++fn) {
                size_t addr = ((size_t)b * CC + m) * NN + n0 + fn * 16 + l15;
                out[addr] = fmaf(g, acc[fm][fn][r] + bpv, x[addr]);
            }
        }
    }
}

extern "C" void kernel_launch(void* const* d_in, const int* in_sizes, int n_in,
                              void* d_out, int out_size, void* d_ws, size_t ws_size,
                              hipStream_t stream)
{
    const float* x     = (const float*)d_in[0];
    const float* Wq    = (const float*)d_in[1];
    const float* bq    = (const float*)d_in[2];
    const float* Wk    = (const float*)d_in[3];
    const float* bk    = (const float*)d_in[4];
    const float* Wv    = (const float*)d_in[5];
    const float* bv    = (const float*)d_in[6];
    const float* Wp    = (const float*)d_in[7];
    const float* bp    = (const float*)d_in[8];
    const float* gamma = (const float*)d_in[9];
    float* out = (float*)d_out;

    ushort* qbw = (ushort*)d_ws;                        // B*N*32  bf16 = 1 MB
    ushort* kbw = qbw + (size_t)BB * NN * DD;           // B*N*32  bf16 = 1 MB
    ushort* vbw = kbw + (size_t)BB * NN * DD;           // B*C*N   bf16 = 8 MB
    ushort* aoT = vbw + (size_t)BB * CC * NN;           // B*N*C   bf16 = 8 MB

    qkv_mfma<<<dim3(NN / 64, 5, BB), 64, 0, stream>>>(x, Wq, bq, Wk, bk, Wv, bv, qbw, kbw, vbw);
    attn_mfma<<<dim3(8, 32, 2), 512, 0, stream>>>(qbw, kbw, vbw, aoT);
    proj_mfma<<<dim3(NN / 256, CC / 64, BB), 256, 0, stream>>>(aoT, Wp, bp, x, gamma, out);
}

// Round 6
// 226.752 us; speedup vs baseline: 1.3252x; 1.3252x over previous
//
#include <hip/hip_runtime.h>
#include <math.h>

#define BB 4
#define CC 256
#define DD 32
#define NN 4096

typedef __attribute__((ext_vector_type(8))) short short8;
typedef __attribute__((ext_vector_type(4))) float floatx4;
typedef __attribute__((ext_vector_type(4))) int intx4;

#define SCALEF (0.17677669529663687f * 1.4426950408889634f)  // 1/sqrt(32)*log2(e)

// float -> bf16 round-to-nearest-even
__device__ __forceinline__ ushort f2bf(float f) {
    unsigned int u = __builtin_bit_cast(unsigned int, f);
    u += 0x7FFFu + ((u >> 16) & 1u);
    return (ushort)(u >> 16);
}
// pack two floats' bf16 truncations into one dword with a single v_perm_b32
__device__ __forceinline__ int pk_trunc(float a, float b) {
    return (int)__builtin_amdgcn_perm(__builtin_bit_cast(unsigned, b),
                                      __builtin_bit_cast(unsigned, a),
                                      0x07060302u);
}
__device__ __forceinline__ float fast_exp2(float x) {
#if __has_builtin(__builtin_amdgcn_exp2f)
    return __builtin_amdgcn_exp2f(x);
#else
    return exp2f(x);
#endif
}

// ---------------------------------------------------------------------------
// Kernel 1: MFMA QKV projection.  Wave tile = 64o x 32n (acc 8 frags = 32
// VGPRs) -> 2560 waves (2.5/SIMD) for latency hiding; 256-thr blocks.
// A-frags: fp32 W loads + v_perm pack (L1/L2-hot).  B-frags: 8 scalar fp32
// x loads (stride N) + pack.  q-scale*log2(e) folded into Wq/bq.
// Outputs bf16: qb,kb (B,N,32), vb (B,C,N).
// ---------------------------------------------------------------------------
__global__ __launch_bounds__(256) void qkv_mfma(
    const float* __restrict__ x,
    const float* __restrict__ Wq, const float* __restrict__ bq,
    const float* __restrict__ Wk, const float* __restrict__ bk,
    const float* __restrict__ Wv, const float* __restrict__ bv,
    ushort* __restrict__ qb, ushort* __restrict__ kb, ushort* __restrict__ vb)
{
    const int t = threadIdx.x;
    const int wave = t >> 6;
    const int lane = t & 63;
    const int l15 = lane & 15, qd = lane >> 4;
    const int b = blockIdx.z, m0 = blockIdx.y * 64;
    const int n0 = blockIdx.x * 128 + wave * 32;
    const float* xb = x + (size_t)b * CC * NN;
    const bool isqk = (m0 == 0);

    const float* wr[4];
    if (isqk) {
        wr[0] = Wq + (size_t)l15 * CC;
        wr[1] = Wq + (size_t)(16 + l15) * CC;
        wr[2] = Wk + (size_t)l15 * CC;
        wr[3] = Wk + (size_t)(16 + l15) * CC;
    } else {
        #pragma unroll
        for (int f = 0; f < 4; ++f) wr[f] = Wv + (size_t)(m0 - 64 + f * 16 + l15) * CC;
    }

    floatx4 z = {0.f, 0.f, 0.f, 0.f};
    floatx4 acc[4][2];
    #pragma unroll
    for (int i = 0; i < 4; ++i) { acc[i][0] = z; acc[i][1] = z; }

    for (int k0 = 0; k0 < CC; k0 += 32) {
        short8 af[4], bf[2];
        #pragma unroll
        for (int f = 0; f < 4; ++f) {
            const float* p = wr[f] + k0 + qd * 8;
            float w[8];
            #pragma unroll
            for (int j = 0; j < 8; ++j) w[j] = p[j];
            if (isqk && f < 2) {
                #pragma unroll
                for (int j = 0; j < 8; ++j) w[j] *= SCALEF;
            }
            intx4 d;
            d[0] = pk_trunc(w[0], w[1]); d[1] = pk_trunc(w[2], w[3]);
            d[2] = pk_trunc(w[4], w[5]); d[3] = pk_trunc(w[6], w[7]);
            af[f] = __builtin_bit_cast(short8, d);
        }
        #pragma unroll
        for (int f = 0; f < 2; ++f) {
            const float* p = xb + (size_t)(k0 + qd * 8) * NN + n0 + f * 16 + l15;
            float xv[8];
            #pragma unroll
            for (int j = 0; j < 8; ++j) xv[j] = p[(size_t)j * NN];
            intx4 d;
            d[0] = pk_trunc(xv[0], xv[1]); d[1] = pk_trunc(xv[2], xv[3]);
            d[2] = pk_trunc(xv[4], xv[5]); d[3] = pk_trunc(xv[6], xv[7]);
            bf[f] = __builtin_bit_cast(short8, d);
        }
        #pragma unroll
        for (int fm = 0; fm < 4; ++fm)
            #pragma unroll
            for (int fn = 0; fn < 2; ++fn)
                acc[fm][fn] = __builtin_amdgcn_mfma_f32_16x16x32_bf16(af[fm], bf[fn], acc[fm][fn], 0, 0, 0);
    }

    #pragma unroll
    for (int fm = 0; fm < 4; ++fm) {
        #pragma unroll
        for (int r = 0; r < 4; ++r) {
            int o = m0 + fm * 16 + qd * 4 + r;
            if (isqk) {
                if (fm < 2) {
                    float bo = bq[o] * SCALEF;
                    #pragma unroll
                    for (int fn = 0; fn < 2; ++fn)
                        qb[((size_t)b * NN + n0 + fn * 16 + l15) * DD + o] = f2bf(acc[fm][fn][r] + bo);
                } else {
                    float bo = bk[o - 32];
                    #pragma unroll
                    for (int fn = 0; fn < 2; ++fn)
                        kb[((size_t)b * NN + n0 + fn * 16 + l15) * DD + (o - 32)] = f2bf(acc[fm][fn][r] + bo);
                }
            } else {
                float bo = bv[o - 64];
                #pragma unroll
                for (int fn = 0; fn < 2; ++fn)
                    vb[((size_t)b * CC + (o - 64)) * NN + n0 + fn * 16 + l15] = f2bf(acc[fm][fn][r] + bo);
            }
        }
    }
}

// ---------------------------------------------------------------------------
// Kernel 2: MFMA flash attention, 4-way key-split, 256-thr blocks.
// Block = 4 waves = 4 key-quarters of one (q-tile, ch-group); wave = 64q x
// 64ch over 1024 keys.  No forced occupancy cap (R5's spilled); no explicit
// prefetch (TLP at ~3 waves/SIMD hides load latency); per-f transient S
// processing (R4 structure).  Partial O/l additive (no max-subtraction),
// 3-barrier LDS tree.  Grid (8,32,4): x=XCD slot, batch=x/2 pins each
// batch's K/V to 2 XCDs' L2.
// ---------------------------------------------------------------------------
__global__ __launch_bounds__(256) void attn_mfma(
    const ushort* __restrict__ qb, const ushort* __restrict__ kb,
    const ushort* __restrict__ vb, ushort* __restrict__ aoT)
{
    __shared__ float red[2][4096];   // [slot][((f*4+ct)*4+r)*64 + lane]
    __shared__ float lred[2][64];    // [slot][f*16 + q]

    const int t = threadIdx.x;
    const int kh = t >> 6;               // key-quarter 0..3
    const int lane = t & 63;
    const int l15 = lane & 15;
    const int qd = lane >> 4;
    const int slot = blockIdx.x;         // ~XCD id (round-robin heuristic)
    const int b = slot >> 1;             // 2 XCDs per batch
    const int qt = (slot & 1) * 32 + blockIdx.y;
    const int q0 = qt * 64;
    const int c0 = blockIdx.z * 64;

    const ushort* krow = kb + ((size_t)b * NN + kh * 1024 + l15) * DD + qd * 8;
    const ushort* vrow = vb + ((size_t)b * CC + c0 + l15) * (size_t)NN + kh * 1024 + qd * 8;

    short8 qf[4];
    #pragma unroll
    for (int f = 0; f < 4; ++f)
        qf[f] = *(const short8*)(qb + ((size_t)b * NN + q0 + f * 16 + l15) * DD + qd * 8);

    const short8 ones = {0x3F80, 0x3F80, 0x3F80, 0x3F80, 0x3F80, 0x3F80, 0x3F80, 0x3F80};

    floatx4 z = {0.f, 0.f, 0.f, 0.f};
    floatx4 acc[4][4];   // [qfrag][chfrag]
    floatx4 accl[4];
    #pragma unroll
    for (int f = 0; f < 4; ++f) {
        accl[f] = z;
        #pragma unroll
        for (int c = 0; c < 4; ++c) acc[f][c] = z;
    }

    const int base  = (qd & 1) * 32 + l15;   // proven transpose lane mapping
    const int base2 = base + 16;
    const bool hi = (lane >= 32);

    for (int kt = 0; kt < 32; ++kt) {
        short8 kf0 = *(const short8*)(krow);
        short8 kf1 = *(const short8*)(krow + 16 * DD);
        short8 vf[4];
        #pragma unroll
        for (int ct = 0; ct < 4; ++ct)
            vf[ct] = *(const short8*)(vrow + (size_t)ct * 16 * NN);
        krow += 32 * DD;
        vrow += 32;

        short8 pt[4];
        #pragma unroll
        for (int f = 0; f < 4; ++f) {
            floatx4 s0 = __builtin_amdgcn_mfma_f32_16x16x32_bf16(kf0, qf[f], z, 0, 0, 0);
            floatx4 s1 = __builtin_amdgcn_mfma_f32_16x16x32_bf16(kf1, qf[f], z, 0, 0, 0);

            float e00 = fast_exp2(s0[0]), e01 = fast_exp2(s0[1]);
            float e02 = fast_exp2(s0[2]), e03 = fast_exp2(s0[3]);
            float e10 = fast_exp2(s1[0]), e11 = fast_exp2(s1[1]);
            float e12 = fast_exp2(s1[2]), e13 = fast_exp2(s1[3]);

            int A0 = pk_trunc(e00, e01);
            int A1 = pk_trunc(e02, e03);
            int B0 = pk_trunc(e10, e11);
            int B1 = pk_trunc(e12, e13);

            int w0a = __shfl(A0, base);  int w0b = __shfl(B0, base);
            int w1a = __shfl(A1, base);  int w1b = __shfl(B1, base);
            int w2a = __shfl(A0, base2); int w2b = __shfl(B0, base2);
            int w3a = __shfl(A1, base2); int w3b = __shfl(B1, base2);

            intx4 ptd;
            ptd[0] = hi ? w0b : w0a;
            ptd[1] = hi ? w1b : w1a;
            ptd[2] = hi ? w2b : w2a;
            ptd[3] = hi ? w3b : w3a;
            pt[f] = __builtin_bit_cast(short8, ptd);
        }

        #pragma unroll
        for (int f = 0; f < 4; ++f)
            accl[f] = __builtin_amdgcn_mfma_f32_16x16x32_bf16(ones, pt[f], accl[f], 0, 0, 0);

        #pragma unroll
        for (int ct = 0; ct < 4; ++ct)
            #pragma unroll
            for (int f = 0; f < 4; ++f)
                acc[f][ct] = __builtin_amdgcn_mfma_f32_16x16x32_bf16(vf[ct], pt[f], acc[f][ct], 0, 0, 0);
    }

    float lsum[4];
    #pragma unroll
    for (int f = 0; f < 4; ++f) lsum[f] = accl[f][0];

    // ---- reduction tree over key-quarters: (0+=1, 2+=3), then 0+=2 ----
    if (kh & 1) {
        const int s = kh >> 1;
        #pragma unroll
        for (int f = 0; f < 4; ++f)
            #pragma unroll
            for (int ct = 0; ct < 4; ++ct)
                #pragma unroll
                for (int r = 0; r < 4; ++r)
                    red[s][((f * 4 + ct) * 4 + r) * 64 + lane] = acc[f][ct][r];
        if (qd == 0)
            #pragma unroll
            for (int f = 0; f < 4; ++f) lred[s][f * 16 + l15] = lsum[f];
    }
    __syncthreads();
    if (!(kh & 1)) {
        const int s = kh >> 1;
        #pragma unroll
        for (int f = 0; f < 4; ++f) {
            #pragma unroll
            for (int ct = 0; ct < 4; ++ct)
                #pragma unroll
                for (int r = 0; r < 4; ++r)
                    acc[f][ct][r] += red[s][((f * 4 + ct) * 4 + r) * 64 + lane];
            lsum[f] += lred[s][f * 16 + l15];
        }
    }
    __syncthreads();
    if (kh == 2) {
        #pragma unroll
        for (int f = 0; f < 4; ++f)
            #pragma unroll
            for (int ct = 0; ct < 4; ++ct)
                #pragma unroll
                for (int r = 0; r < 4; ++r)
                    red[0][((f * 4 + ct) * 4 + r) * 64 + lane] = acc[f][ct][r];
        if (qd == 0)
            #pragma unroll
            for (int f = 0; f < 4; ++f) lred[0][f * 16 + l15] = lsum[f];
    }
    __syncthreads();
    if (kh == 0) {
        #pragma unroll
        for (int f = 0; f < 4; ++f) {
            #pragma unroll
            for (int ct = 0; ct < 4; ++ct)
                #pragma unroll
                for (int r = 0; r < 4; ++r)
                    acc[f][ct][r] += red[0][((f * 4 + ct) * 4 + r) * 64 + lane];
            lsum[f] += lred[0][f * 16 + l15];
        }
        #pragma unroll
        for (int f = 0; f < 4; ++f) {
            const float inv = 1.0f / lsum[f];
            ushort* dst = aoT + ((size_t)b * NN + q0 + f * 16 + l15) * CC + c0 + qd * 4;
            #pragma unroll
            for (int ct = 0; ct < 4; ++ct) {
                ushort4 h;
                h.x = f2bf(acc[f][ct][0] * inv);
                h.y = f2bf(acc[f][ct][1] * inv);
                h.z = f2bf(acc[f][ct][2] * inv);
                h.w = f2bf(acc[f][ct][3] * inv);
                *(ushort4*)(dst + ct * 16) = h;
            }
        }
    }
}

// ---------------------------------------------------------------------------
// Kernel 3: MFMA output projection + residual.  gemm_bt form, A-frags cast
// from fp32 Wp in-register, B-frags straight short8 loads from bf16 aoT.
// out = x + gamma*(Wp@ao + bp).
// ---------------------------------------------------------------------------
__global__ __launch_bounds__(256) void proj_mfma(
    const ushort* __restrict__ aoT, const float* __restrict__ Wp,
    const float* __restrict__ bp, const float* __restrict__ x,
    const float* __restrict__ gamma, float* __restrict__ out)
{
    const int t = threadIdx.x;
    const int wave = t >> 6;
    const int lane = t & 63;
    const int l15 = lane & 15;
    const int qd = lane >> 4;
    const int b = blockIdx.z;
    const int m0 = blockIdx.y * 64;
    const int n0 = blockIdx.x * 256 + wave * 64;

    floatx4 z = {0.f, 0.f, 0.f, 0.f};
    floatx4 acc[4][4];   // [fm][fn]
    #pragma unroll
    for (int i = 0; i < 4; ++i)
        #pragma unroll
        for (int j = 0; j < 4; ++j) acc[i][j] = z;

    const ushort* arow = aoT + ((size_t)b * NN + n0 + l15) * CC + qd * 8;
    const float* wrow = Wp + (size_t)(m0 + l15) * CC + qd * 8;

    #pragma unroll
    for (int k0 = 0; k0 < CC; k0 += 32) {
        short8 af[4], bf[4];
        #pragma unroll
        for (int f = 0; f < 4; ++f) {
            const float* p = wrow + (size_t)f * 16 * CC + k0;
            intx4 d;
            d[0] = pk_trunc(p[0], p[1]); d[1] = pk_trunc(p[2], p[3]);
            d[2] = pk_trunc(p[4], p[5]); d[3] = pk_trunc(p[6], p[7]);
            af[f] = __builtin_bit_cast(short8, d);
            bf[f] = *(const short8*)(arow + (size_t)f * 16 * CC + k0);
        }
        #pragma unroll
        for (int fm = 0; fm < 4; ++fm)
            #pragma unroll
            for (int fn = 0; fn < 4; ++fn)
                acc[fm][fn] = __builtin_amdgcn_mfma_f32_16x16x32_bf16(af[fm], bf[fn], acc[fm][fn], 0, 0, 0);
    }

    const float g = gamma[0];
    #pragma unroll
    for (int fm = 0; fm < 4; ++fm) {
        #pragma unroll
        for (int r = 0; r < 4; ++r) {
            int m = m0 + fm * 16 + qd * 4 + r;
            float bpv = bp[m];
            #pragma unroll
            for (int fn = 0; fn < 4; ++fn) {
                size_t addr = ((size_t)b * CC + m) * NN + n0 + fn * 16 + l15;
                out[addr] = fmaf(g, acc[fm][fn][r] + bpv, x[addr]);
            }
        }
    }
}

extern "C" void kernel_launch(void* const* d_in, const int* in_sizes, int n_in,
                              void* d_out, int out_size, void* d_ws, size_t ws_size,
                              hipStream_t stream)
{
    const float* x     = (const float*)d_in[0];
    const float* Wq    = (const float*)d_in[1];
    const float* bq    = (const float*)d_in[2];
    const float* Wk    = (const float*)d_in[3];
    const float* bk    = (const float*)d_in[4];
    const float* Wv    = (const float*)d_in[5];
    const float* bv    = (const float*)d_in[6];
    const float* Wp    = (const float*)d_in[7];
    const float* bp    = (const float*)d_in[8];
    const float* gamma = (const float*)d_in[9];
    float* out = (float*)d_out;

    ushort* qbw = (ushort*)d_ws;                        // B*N*32  bf16 = 1 MB
    ushort* kbw = qbw + (size_t)BB * NN * DD;           // B*N*32  bf16 = 1 MB
    ushort* vbw = kbw + (size_t)BB * NN * DD;           // B*C*N   bf16 = 8 MB
    ushort* aoT = vbw + (size_t)BB * CC * NN;           // B*N*C   bf16 = 8 MB

    qkv_mfma<<<dim3(NN / 128, 5, BB), 256, 0, stream>>>(x, Wq, bq, Wk, bk, Wv, bv, qbw, kbw, vbw);
    attn_mfma<<<dim3(8, 32, 4), 256, 0, stream>>>(qbw, kbw, vbw, aoT);
    proj_mfma<<<dim3(NN / 256, CC / 64, BB), 256, 0, stream>>>(aoT, Wp, bp, x, gamma, out);
}